// Round 1
// baseline (156.175 us; speedup 1.0000x reference)
//
#include <hip/hip_runtime.h>
#include <hip/hip_bf16.h>

// MultiBox loss: three scalars (closs, rloss, loss) over N=2M anchors.
// Memory-bound reduction: 44 B/row, ~88 MB total.

__device__ __forceinline__ float smooth_l1(float d) {
    float ad = fabsf(d);
    return (ad < 1.0f) ? 0.5f * d * d : ad - 0.5f;
}

__global__ __launch_bounds__(256) void mbl_reduce(
        const float2* __restrict__ cout,   // [N] of float2
        const float4* __restrict__ rout,   // [N] of float4
        const int*    __restrict__ cls,    // [N]
        const float4* __restrict__ regt,   // [N] of float4
        float* __restrict__ ws,            // ws[0]=S_ce, ws[1]=S_sl1
        int n) {
    float s1 = 0.0f;  // sum of CE over selected (label 0 or 1) rows
    float s2 = 0.0f;  // sum of raw smooth-L1 (all 4 coords) over positive rows

    int stride = gridDim.x * blockDim.x;
    for (int i = blockIdx.x * blockDim.x + threadIdx.x; i < n; i += stride) {
        int lbl = cls[i];
        if (lbl != 2) {
            float2 c = cout[i];
            float m = fmaxf(c.x, c.y);
            float lse = m + __logf(__expf(c.x - m) + __expf(c.y - m));
            s1 += lse - (lbl == 1 ? c.y : c.x);
        }
        if (lbl == 1) {
            float4 r = rout[i];
            float4 t = regt[i];
            s2 += smooth_l1(r.x - t.x) + smooth_l1(r.y - t.y)
                + smooth_l1(r.z - t.z) + smooth_l1(r.w - t.w);
        }
    }

    // wave-64 shuffle reduction
    for (int off = 32; off > 0; off >>= 1) {
        s1 += __shfl_down(s1, off, 64);
        s2 += __shfl_down(s2, off, 64);
    }
    __shared__ float ls1[4], ls2[4];
    int lane = threadIdx.x & 63;
    int wid  = threadIdx.x >> 6;
    if (lane == 0) { ls1[wid] = s1; ls2[wid] = s2; }
    __syncthreads();
    if (threadIdx.x == 0) {
        float a = ls1[0] + ls1[1] + ls1[2] + ls1[3];
        float b = ls2[0] + ls2[1] + ls2[2] + ls2[3];
        atomicAdd(&ws[0], a);
        atomicAdd(&ws[1], b);
    }
}

__global__ void mbl_finalize(const float* __restrict__ ws, float* __restrict__ out) {
    // closs = S_ce / 64 ; rloss = (S_sl1 / 4) / 16 = S_sl1 / 64
    float closs = ws[0] * (1.0f / 64.0f);
    float rloss = ws[1] * (1.0f / 64.0f);
    out[0] = closs;
    out[1] = rloss;
    out[2] = closs + 10.0f * rloss;
}

extern "C" void kernel_launch(void* const* d_in, const int* in_sizes, int n_in,
                              void* d_out, int out_size, void* d_ws, size_t ws_size,
                              hipStream_t stream) {
    const float2* cout = (const float2*)d_in[0];
    const float4* rout = (const float4*)d_in[1];
    const int*    cls  = (const int*)d_in[2];
    const float4* regt = (const float4*)d_in[3];
    float* out = (float*)d_out;
    float* ws  = (float*)d_ws;

    int n = in_sizes[2];  // N rows (cls_t element count)

    hipMemsetAsync(ws, 0, 2 * sizeof(float), stream);

    const int block = 256;
    const int grid  = 2048;  // ~3.8 rows/thread grid-stride; 8 blocks/CU
    mbl_reduce<<<grid, block, 0, stream>>>(cout, rout, cls, regt, ws, n);
    mbl_finalize<<<1, 1, 0, stream>>>(ws, out);
}

// Round 2
// 111.243 us; speedup vs baseline: 1.4039x; 1.4039x over previous
//
#include <hip/hip_runtime.h>
#include <hip/hip_bf16.h>

// MultiBox loss: three scalars (closs, rloss, loss) over N=2M anchors.
// Streaming reduction, 44 B/row, ~88 MB total. Unconditional coalesced loads
// + arithmetic masking (random labels mean ~all cache lines are needed anyway;
// predicated loads only added latency-serialization, not BW savings).

__device__ __forceinline__ float smooth_l1(float d) {
    float ad = fabsf(d);
    return (ad < 1.0f) ? 0.5f * d * d : ad - 0.5f;
}

__device__ __forceinline__ float ce_term(float x, float y, int lbl) {
    // cross-entropy of softmax([x,y]) vs label, 0 if lbl==2 (ignored)
    float m = fmaxf(x, y);
    float lse = m + __logf(__expf(x - m) + __expf(y - m));
    float ce = lse - ((lbl == 1) ? y : x);
    return (lbl != 2) ? ce : 0.0f;
}

__device__ __forceinline__ float sl1_row(float4 r, float4 t) {
    return smooth_l1(r.x - t.x) + smooth_l1(r.y - t.y)
         + smooth_l1(r.z - t.z) + smooth_l1(r.w - t.w);
}

#define NBLOCKS 1024

__global__ __launch_bounds__(256) void mbl_reduce(
        const float4* __restrict__ cout2,  // [N/2] float4 (2 rows per vec)
        const float4* __restrict__ rout,   // [N]   float4
        const int4*   __restrict__ cls4,   // [N/4] int4
        const float4* __restrict__ regt,   // [N]   float4
        float* __restrict__ partials,      // [2*NBLOCKS]
        int ngroups, int n) {
    float s1 = 0.0f;  // sum CE over selected rows
    float s2 = 0.0f;  // sum raw smooth-L1 over positive rows

    int stride = gridDim.x * blockDim.x;
    for (int g = blockIdx.x * blockDim.x + threadIdx.x; g < ngroups; g += stride) {
        // Issue all 11 independent 16B loads up front (MLP), then compute.
        int4   l  = cls4[g];
        float4 c0 = cout2[2 * g];
        float4 c1 = cout2[2 * g + 1];
        float4 r0 = rout[4 * g],  r1 = rout[4 * g + 1];
        float4 r2 = rout[4 * g + 2], r3 = rout[4 * g + 3];
        float4 t0 = regt[4 * g],  t1 = regt[4 * g + 1];
        float4 t2 = regt[4 * g + 2], t3 = regt[4 * g + 3];

        s1 += ce_term(c0.x, c0.y, l.x) + ce_term(c0.z, c0.w, l.y)
            + ce_term(c1.x, c1.y, l.z) + ce_term(c1.z, c1.w, l.w);

        s2 += ((l.x == 1) ? sl1_row(r0, t0) : 0.0f)
            + ((l.y == 1) ? sl1_row(r1, t1) : 0.0f)
            + ((l.z == 1) ? sl1_row(r2, t2) : 0.0f)
            + ((l.w == 1) ? sl1_row(r3, t3) : 0.0f);
    }

    // remainder rows (n not divisible by 4) — one thread, scalar
    if (blockIdx.x == 0 && threadIdx.x == 0) {
        const float2* coutS = (const float2*)cout2;
        const int*    clsS  = (const int*)cls4;
        for (int i = 4 * ngroups; i < n; ++i) {
            int lbl = clsS[i];
            float2 c = coutS[i];
            s1 += ce_term(c.x, c.y, lbl);
            s2 += (lbl == 1) ? sl1_row(rout[i], regt[i]) : 0.0f;
        }
    }

    // wave-64 shuffle reduction
    for (int off = 32; off > 0; off >>= 1) {
        s1 += __shfl_down(s1, off, 64);
        s2 += __shfl_down(s2, off, 64);
    }
    __shared__ float ls1[4], ls2[4];
    int lane = threadIdx.x & 63;
    int wid  = threadIdx.x >> 6;
    if (lane == 0) { ls1[wid] = s1; ls2[wid] = s2; }
    __syncthreads();
    if (threadIdx.x == 0) {
        partials[2 * blockIdx.x]     = ls1[0] + ls1[1] + ls1[2] + ls1[3];
        partials[2 * blockIdx.x + 1] = ls2[0] + ls2[1] + ls2[2] + ls2[3];
    }
}

__global__ __launch_bounds__(256) void mbl_finalize(
        const float* __restrict__ partials, float* __restrict__ out) {
    float s1 = 0.0f, s2 = 0.0f;
    for (int b = threadIdx.x; b < NBLOCKS; b += 256) {
        s1 += partials[2 * b];
        s2 += partials[2 * b + 1];
    }
    for (int off = 32; off > 0; off >>= 1) {
        s1 += __shfl_down(s1, off, 64);
        s2 += __shfl_down(s2, off, 64);
    }
    __shared__ float ls1[4], ls2[4];
    int lane = threadIdx.x & 63;
    int wid  = threadIdx.x >> 6;
    if (lane == 0) { ls1[wid] = s1; ls2[wid] = s2; }
    __syncthreads();
    if (threadIdx.x == 0) {
        float S1 = ls1[0] + ls1[1] + ls1[2] + ls1[3];
        float S2 = ls2[0] + ls2[1] + ls2[2] + ls2[3];
        float closs = S1 * (1.0f / 64.0f);
        float rloss = S2 * (1.0f / 64.0f);  // (S2/4)/16
        out[0] = closs;
        out[1] = rloss;
        out[2] = closs + 10.0f * rloss;
    }
}

extern "C" void kernel_launch(void* const* d_in, const int* in_sizes, int n_in,
                              void* d_out, int out_size, void* d_ws, size_t ws_size,
                              hipStream_t stream) {
    const float4* cout2 = (const float4*)d_in[0];
    const float4* rout  = (const float4*)d_in[1];
    const int4*   cls4  = (const int4*)d_in[2];
    const float4* regt  = (const float4*)d_in[3];
    float* out      = (float*)d_out;
    float* partials = (float*)d_ws;  // 2*NBLOCKS floats; every slot written, no memset needed

    int n = in_sizes[2];
    int ngroups = n / 4;

    mbl_reduce<<<NBLOCKS, 256, 0, stream>>>(cout2, rout, cls4, regt, partials, ngroups, n);
    mbl_finalize<<<1, 256, 0, stream>>>(partials, out);
}

// Round 3
// 108.641 us; speedup vs baseline: 1.4375x; 1.0240x over previous
//
#include <hip/hip_runtime.h>
#include <hip/hip_bf16.h>

// MultiBox loss: three scalars (closs, rloss, loss) over N=2M anchors.
// Streaming reduction, 44 B/row, ~88 MB total. Unconditional coalesced loads
// + arithmetic masking. 2048 blocks x 256 threads => ~1 four-row group per
// thread: all 11 independent 16B loads issue once, no loop-carried dep.

__device__ __forceinline__ float smooth_l1(float d) {
    float ad = fabsf(d);
    return (ad < 1.0f) ? 0.5f * d * d : ad - 0.5f;
}

__device__ __forceinline__ float ce_term(float x, float y, int lbl) {
    // cross-entropy of softmax([x,y]) vs label, 0 if lbl==2 (ignored)
    float m = fmaxf(x, y);
    float lse = m + __logf(__expf(x - m) + __expf(y - m));
    float ce = lse - ((lbl == 1) ? y : x);
    return (lbl != 2) ? ce : 0.0f;
}

__device__ __forceinline__ float sl1_row(float4 r, float4 t) {
    return smooth_l1(r.x - t.x) + smooth_l1(r.y - t.y)
         + smooth_l1(r.z - t.z) + smooth_l1(r.w - t.w);
}

#define NBLOCKS 2048

__global__ __launch_bounds__(256) void mbl_reduce(
        const float4* __restrict__ cout2,  // [N/2] float4 (2 rows per vec)
        const float4* __restrict__ rout,   // [N]   float4
        const int4*   __restrict__ cls4,   // [N/4] int4
        const float4* __restrict__ regt,   // [N]   float4
        float* __restrict__ partials,      // [2*NBLOCKS]
        int ngroups, int n) {
    float s1 = 0.0f;  // sum CE over selected rows
    float s2 = 0.0f;  // sum raw smooth-L1 over positive rows

    int stride = gridDim.x * blockDim.x;
    for (int g = blockIdx.x * blockDim.x + threadIdx.x; g < ngroups; g += stride) {
        // Issue all 11 independent 16B loads up front (MLP), then compute.
        int4   l  = cls4[g];
        float4 c0 = cout2[2 * g];
        float4 c1 = cout2[2 * g + 1];
        float4 r0 = rout[4 * g],     r1 = rout[4 * g + 1];
        float4 r2 = rout[4 * g + 2], r3 = rout[4 * g + 3];
        float4 t0 = regt[4 * g],     t1 = regt[4 * g + 1];
        float4 t2 = regt[4 * g + 2], t3 = regt[4 * g + 3];

        s1 += ce_term(c0.x, c0.y, l.x) + ce_term(c0.z, c0.w, l.y)
            + ce_term(c1.x, c1.y, l.z) + ce_term(c1.z, c1.w, l.w);

        s2 += ((l.x == 1) ? sl1_row(r0, t0) : 0.0f)
            + ((l.y == 1) ? sl1_row(r1, t1) : 0.0f)
            + ((l.z == 1) ? sl1_row(r2, t2) : 0.0f)
            + ((l.w == 1) ? sl1_row(r3, t3) : 0.0f);
    }

    // remainder rows (n not divisible by 4) — one thread, scalar
    if (blockIdx.x == 0 && threadIdx.x == 0) {
        const float2* coutS = (const float2*)cout2;
        const int*    clsS  = (const int*)cls4;
        for (int i = 4 * ngroups; i < n; ++i) {
            int lbl = clsS[i];
            float2 c = coutS[i];
            s1 += ce_term(c.x, c.y, lbl);
            s2 += (lbl == 1) ? sl1_row(rout[i], regt[i]) : 0.0f;
        }
    }

    // wave-64 shuffle reduction
    for (int off = 32; off > 0; off >>= 1) {
        s1 += __shfl_down(s1, off, 64);
        s2 += __shfl_down(s2, off, 64);
    }
    __shared__ float ls1[4], ls2[4];
    int lane = threadIdx.x & 63;
    int wid  = threadIdx.x >> 6;
    if (lane == 0) { ls1[wid] = s1; ls2[wid] = s2; }
    __syncthreads();
    if (threadIdx.x == 0) {
        partials[2 * blockIdx.x]     = ls1[0] + ls1[1] + ls1[2] + ls1[3];
        partials[2 * blockIdx.x + 1] = ls2[0] + ls2[1] + ls2[2] + ls2[3];
    }
}

__global__ __launch_bounds__(256) void mbl_finalize(
        const float* __restrict__ partials, float* __restrict__ out) {
    float s1 = 0.0f, s2 = 0.0f;
    for (int b = threadIdx.x; b < NBLOCKS; b += 256) {
        s1 += partials[2 * b];
        s2 += partials[2 * b + 1];
    }
    for (int off = 32; off > 0; off >>= 1) {
        s1 += __shfl_down(s1, off, 64);
        s2 += __shfl_down(s2, off, 64);
    }
    __shared__ float ls1[4], ls2[4];
    int lane = threadIdx.x & 63;
    int wid  = threadIdx.x >> 6;
    if (lane == 0) { ls1[wid] = s1; ls2[wid] = s2; }
    __syncthreads();
    if (threadIdx.x == 0) {
        float S1 = ls1[0] + ls1[1] + ls1[2] + ls1[3];
        float S2 = ls2[0] + ls2[1] + ls2[2] + ls2[3];
        float closs = S1 * (1.0f / 64.0f);
        float rloss = S2 * (1.0f / 64.0f);  // (S2/4)/16
        out[0] = closs;
        out[1] = rloss;
        out[2] = closs + 10.0f * rloss;
    }
}

extern "C" void kernel_launch(void* const* d_in, const int* in_sizes, int n_in,
                              void* d_out, int out_size, void* d_ws, size_t ws_size,
                              hipStream_t stream) {
    const float4* cout2 = (const float4*)d_in[0];
    const float4* rout  = (const float4*)d_in[1];
    const int4*   cls4  = (const int4*)d_in[2];
    const float4* regt  = (const float4*)d_in[3];
    float* out      = (float*)d_out;
    float* partials = (float*)d_ws;  // 2*NBLOCKS floats; every slot written, no memset needed

    int n = in_sizes[2];
    int ngroups = n / 4;

    mbl_reduce<<<NBLOCKS, 256, 0, stream>>>(cout2, rout, cls4, regt, partials, ngroups, n);
    mbl_finalize<<<1, 256, 0, stream>>>(partials, out);
}